// Round 19
// baseline (6200.454 us; speedup 1.0000x reference)
//
#include <hip/hip_runtime.h>
#include <hip/hip_bf16.h>

#define T_SEQ 512
#define BATCH 64
#define IN0   128
#define HID   512
#define OUTF  256
#define G4    (4*HID)     // 2048 gate rows
#define NWG_L 64          // workgroups per layer (each owns 8 hidden units)
#define FSTR  32          // u32s between flags -> one 128B line per producer
#define RING  8           // L1 h-ring depth (intra-layer skew <= 1, safe)

typedef __attribute__((ext_vector_type(8))) short short8;   // 8 bf16 (MFMA A/B frag)
typedef __attribute__((ext_vector_type(4))) float f32x4;    // MFMA C/D frag
typedef unsigned short u16;
typedef unsigned long long u64;

__device__ __forceinline__ float sigmoidf_(float x) { return 1.f / (1.f + __expf(-x)); }
__device__ __forceinline__ float tanhf_(float x)    { return 1.f - 2.f / (1.f + __expf(2.f * x)); }

__device__ __forceinline__ u16 f2bf(float f) {
    union { float f; unsigned u; } a; a.f = f;
    unsigned u = a.u;
    return (u16)((u + 0x7fffu + ((u >> 16) & 1u)) >> 16);   // RNE
}

// Groupwise poll with backoff (R13, unchanged): wait for producers
// [16*grp, 16*grp+16) >= tgt. Lane l watches flags[(16*grp + (l&15)) * FSTR].
__device__ __forceinline__ void poll_grp(const unsigned* flags, int lane, int grp, unsigned tgt) {
    const unsigned* p = flags + (size_t)(grp * 16 + (lane & 15)) * FSTR;
    unsigned it = 0;
    for (;;) {
        unsigned v = __hip_atomic_load(p, __ATOMIC_RELAXED, __HIP_MEMORY_SCOPE_AGENT);
        if (__all((int)(v >= tgt))) return;
        if (it < 6) __builtin_amdgcn_s_sleep(1);
        else        __builtin_amdgcn_s_sleep(16);
        if ((++it & 1023u) == 0u)
            (void)__hip_atomic_load(p, __ATOMIC_ACQUIRE, __HIP_MEMORY_SCOPE_AGENT);
    }
}

// Tagged group load: 4 K-slices (32 u32 each lane-row) loaded PLAIN (L2-cached,
// cheap); embedded per-word epoch verified; stale fragments retried via sc1
// (IC-direct). Flags are raised WITHOUT a write-ack, so the tag closes the
// flag-before-data window; common case is zero retries on cached loads.
__device__ __forceinline__ void load_grp_tagged(
    const unsigned* rp, unsigned tagv, int grp, short8 (&a)[4])
{
    uint4 lo[4], hi[4];
    #pragma unroll
    for (int j = 0; j < 4; ++j) {
        const uint4* q = reinterpret_cast<const uint4*>(rp + (grp * 4 + j) * 32);
        lo[j] = q[0]; hi[j] = q[1];
    }
    for (;;) {
        unsigned bad = 0;
        #pragma unroll
        for (int j = 0; j < 4; ++j) {
            bool ok = (lo[j].x >> 16) == tagv && (lo[j].y >> 16) == tagv
                   && (lo[j].z >> 16) == tagv && (lo[j].w >> 16) == tagv
                   && (hi[j].x >> 16) == tagv && (hi[j].y >> 16) == tagv
                   && (hi[j].z >> 16) == tagv && (hi[j].w >> 16) == tagv;
            if (!ok) bad |= 1u << j;
        }
        if (__all((int)(bad == 0))) break;
        __builtin_amdgcn_s_sleep(1);
        #pragma unroll
        for (int j = 0; j < 4; ++j) if (bad & (1u << j)) {
            const unsigned* q = rp + (grp * 4 + j) * 32;
            asm volatile("global_load_dwordx4 %0, %2, off sc1\n\t"
                         "global_load_dwordx4 %1, %2, off offset:16 sc1"
                         : "=v"(lo[j]), "=v"(hi[j]) : "v"(q));
        }
        asm volatile("s_waitcnt vmcnt(0)" ::: "memory");
    }
    #pragma unroll
    for (int j = 0; j < 4; ++j) {
        a[j][0] = (short)lo[j].x; a[j][1] = (short)lo[j].y;
        a[j][2] = (short)lo[j].z; a[j][3] = (short)lo[j].w;
        a[j][4] = (short)hi[j].x; a[j][5] = (short)hi[j].y;
        a[j][6] = (short)hi[j].z; a[j][7] = (short)hi[j].w;
    }
}

// ---------------- f32 -> bf16 conversion ----------------
__global__ void cvt_f32_bf16(const float* __restrict__ in, u16* __restrict__ out, int n4) {
    int i = blockIdx.x * blockDim.x + threadIdx.x;
    if (i < n4) {
        float4 v = reinterpret_cast<const float4*>(in)[i];
        ushort4 o;
        o.x = f2bf(v.x); o.y = f2bf(v.y); o.z = f2bf(v.z); o.w = f2bf(v.w);
        reinterpret_cast<ushort4*>(out)[i] = o;
    }
}

// ---------------- fused pipelined 2-layer LSTM (ack-free tagged publish) ------
// WG g in [0,64): layer 0, owns hidden units [8g, 8g+8). WG 64+g: layer 1.
// flags[g*FSTR] = steps completed by WG g (raised WITHOUT write-ack).
// h data: tagged u32 (bf16 | epoch<<16). L0 h lives in y0tag [T][B][H] (also
// the cross-layer pipe); L1 h in an 8-deep ring. Consume: R13 groupwise poll,
// then tagged plain loads (load_grp_tagged). Publish: 4x u64 relaxed stores,
// flag immediately — the vmcnt(0) ack is GONE from the critical path.
template<int LAYER>
__device__ __forceinline__ void run_layer(
    const u16* __restrict__ x_bf,          // L0 input
    const unsigned* __restrict__ dep_tag,  // L1: y0tag (read)
    unsigned* __restrict__ own_tag,        // L0: y0tag; L1: ring
    u16* __restrict__ y1bf,                // L1: plain bf16 out for FC
    const float* __restrict__ wih, const float* /*unused*/,
    const u16* __restrict__ wihb, const u16* __restrict__ whhb,
    const float* __restrict__ bias,
    float* __restrict__ hNout, float* __restrict__ cNout,
    unsigned* flags_own, unsigned* flags_dep, int g,
    u16 (*lds_w)[32][512], float (*lds_g)[33], float (*lds_b)[16],
    unsigned (*lds_h)[8])
{
    constexpr int KIN = (LAYER == 0) ? IN0 : HID;
    constexpr int KS1 = KIN / 32;        // input-part K slices
    constexpr int KS  = KS1 + 16;        // + recurrent K slices

    const int tid  = threadIdx.x;
    const int lane = tid & 63;
    const int w    = tid >> 6;           // wave id -> batch rows 16w..16w+15
    const int ubase = 8 * g;

    // ---- pack weights into LDS in MFMA B-frag order (2 col-tiles) ----
    for (int idx = tid; idx < 2 * KS * 64; idx += 256) {
        int nt  = (idx >= KS * 64) ? 1 : 0;
        int rem = idx - nt * KS * 64;
        int ks = rem >> 6, s = rem & 63, q = s & 15, kq = s >> 4;
        int r = (q >> 2) * HID + ubase + 4 * nt + (q & 3);   // global gate row
        const u16* src = (ks < KS1)
            ? wihb + (size_t)r * KIN + (size_t)ks * 32 + kq * 8
            : whhb + (size_t)r * HID + (size_t)(ks - KS1) * 32 + kq * 8;
        *reinterpret_cast<uint4*>(&lds_w[nt][ks][s * 8]) =
            *reinterpret_cast<const uint4*>(src);
    }
    if (tid < 32) {
        int nt = tid >> 4, q = tid & 15;
        lds_b[nt][q] = bias[(q >> 2) * HID + ubase + 4 * nt + (q & 3)];
    }
    __syncthreads();

    const int pb  = tid & 63;   // pointwise: batch index
    const int pu2 = tid >> 6;   // pointwise: unit-pair index (0..3)
    float c0 = 0.f, c1 = 0.f;

    const int arow = 16 * w + (lane & 15);
    const int koff = (lane >> 4) * 8;

    for (int t = 0; t < T_SEQ; ++t) {
        const unsigned tagv = (unsigned)(t + 1);
        f32x4 ac0[4] = {{0,0,0,0},{0,0,0,0},{0,0,0,0},{0,0,0,0}};
        f32x4 ac1[4] = {{0,0,0,0},{0,0,0,0},{0,0,0,0},{0,0,0,0}};

        // ---- input contribution ----
        if (LAYER == 0) {
            // x[t]: no dependency
            const u16* ap = x_bf + ((size_t)t * BATCH + arow) * KIN + koff;
            short8 a[KS1];
            #pragma unroll
            for (int j = 0; j < KS1; ++j)
                a[j] = *reinterpret_cast<const short8*>(ap + j * 32);
            #pragma unroll
            for (int j = 0; j < KS1; ++j) {
                ac0[j & 3] = __builtin_amdgcn_mfma_f32_16x16x32_bf16(
                    a[j], *reinterpret_cast<const short8*>(&lds_w[0][j][lane * 8]), ac0[j & 3], 0, 0, 0);
                ac1[j & 3] = __builtin_amdgcn_mfma_f32_16x16x32_bf16(
                    a[j], *reinterpret_cast<const short8*>(&lds_w[1][j][lane * 8]), ac1[j & 3], 0, 0, 0);
            }
        } else {
            // y0[t] (tag t+1): groupwise poll on L0 flags, tagged plain loads
            const unsigned* rp = dep_tag + ((size_t)t * BATCH + arow) * HID + koff;
            for (int grp = 0; grp < 4; ++grp) {
                poll_grp(flags_dep, lane, grp, tagv);
                short8 a[4];
                load_grp_tagged(rp, tagv, grp, a);
                #pragma unroll
                for (int j = 0; j < 4; ++j) {
                    int ks = grp * 4 + j;
                    ac0[j] = __builtin_amdgcn_mfma_f32_16x16x32_bf16(
                        a[j], *reinterpret_cast<const short8*>(&lds_w[0][ks][lane * 8]), ac0[j], 0, 0, 0);
                    ac1[j] = __builtin_amdgcn_mfma_f32_16x16x32_bf16(
                        a[j], *reinterpret_cast<const short8*>(&lds_w[1][ks][lane * 8]), ac1[j], 0, 0, 0);
                }
            }
        }

        // ---- recurrent contribution h[t-1] (tag t): groupwise self-paced ----
        if (t > 0) {
            const size_t slot = (LAYER == 0) ? (size_t)(t - 1) : (size_t)((t - 1) & (RING - 1));
            const unsigned* rp = own_tag + (slot * BATCH + arow) * HID + koff;
            for (int grp = 0; grp < 4; ++grp) {
                poll_grp(flags_own, lane, grp, (unsigned)t);
                short8 a[4];
                load_grp_tagged(rp, (unsigned)t, grp, a);
                #pragma unroll
                for (int j = 0; j < 4; ++j) {
                    int ks = grp * 4 + j;
                    ac0[j] = __builtin_amdgcn_mfma_f32_16x16x32_bf16(
                        a[j], *reinterpret_cast<const short8*>(&lds_w[0][KS1 + ks][lane * 8]), ac0[j], 0, 0, 0);
                    ac1[j] = __builtin_amdgcn_mfma_f32_16x16x32_bf16(
                        a[j], *reinterpret_cast<const short8*>(&lds_w[1][KS1 + ks][lane * 8]), ac1[j], 0, 0, 0);
                }
            }
        }

        f32x4 s0 = (ac0[0] + ac0[1]) + (ac0[2] + ac0[3]);
        f32x4 s1 = (ac1[0] + ac1[1]) + (ac1[2] + ac1[3]);
        // D frag: row = 16w + (lane>>4)*4 + j (batch), col = lane&15 (q)
        #pragma unroll
        for (int j = 0; j < 4; ++j) {
            int row = 16 * w + (lane >> 4) * 4 + j;
            lds_g[row][lane & 15]        = s0[j];
            lds_g[row][16 + (lane & 15)] = s1[j];
        }
        __syncthreads();

        // ---- cell update (f32): thread (pb,pu2) owns units 2pu2, 2pu2+1 ----
        {
            const int nt = pu2 >> 1;
            const int dq = (2 * pu2) & 3;
            const float* gr = &lds_g[pb][nt * 16];
            const float* br = lds_b[nt];
            float gi0 = sigmoidf_(gr[dq]      + br[dq]);
            float gf0 = sigmoidf_(gr[4 + dq]  + br[4 + dq]);
            float gg0 = tanhf_(   gr[8 + dq]  + br[8 + dq]);
            float go0 = sigmoidf_(gr[12 + dq] + br[12 + dq]);
            c0 = gf0 * c0 + gi0 * gg0;
            float h0v = go0 * tanhf_(c0);
            float gi1 = sigmoidf_(gr[dq + 1]      + br[dq + 1]);
            float gf1 = sigmoidf_(gr[4 + dq + 1]  + br[4 + dq + 1]);
            float gg1 = tanhf_(   gr[8 + dq + 1]  + br[8 + dq + 1]);
            float go1 = sigmoidf_(gr[12 + dq + 1] + br[12 + dq + 1]);
            c1 = gf1 * c1 + gi1 * gg1;
            float h1v = go1 * tanhf_(c1);

            lds_h[pb][4 * nt + dq]     = (unsigned)f2bf(h0v) | (tagv << 16);
            lds_h[pb][4 * nt + dq + 1] = (unsigned)f2bf(h1v) | (tagv << 16);

            if (t == T_SEQ - 1) {
                const int u0 = ubase + 4 * nt + dq, u1 = u0 + 1;
                hNout[pb * HID + u0] = h0v;
                hNout[pb * HID + u1] = h1v;
                cNout[pb * HID + u0] = c0;
                cNout[pb * HID + u1] = c1;
            }
        }
        __syncthreads();

        // ---- wave-0 ack-free publish: tagged stores, flag immediately ----
        if (w == 0) {
            const unsigned* hr = lds_h[lane];
            u64 q0 = (u64)hr[0] | ((u64)hr[1] << 32);
            u64 q1 = (u64)hr[2] | ((u64)hr[3] << 32);
            u64 q2 = (u64)hr[4] | ((u64)hr[5] << 32);
            u64 q3 = (u64)hr[6] | ((u64)hr[7] << 32);
            const size_t slot = (LAYER == 0) ? (size_t)t : (size_t)(t & (RING - 1));
            u64* hp = reinterpret_cast<u64*>(
                own_tag + (slot * BATCH + lane) * HID + ubase);
            __hip_atomic_store(hp + 0, q0, __ATOMIC_RELAXED, __HIP_MEMORY_SCOPE_AGENT);
            __hip_atomic_store(hp + 1, q1, __ATOMIC_RELAXED, __HIP_MEMORY_SCOPE_AGENT);
            __hip_atomic_store(hp + 2, q2, __ATOMIC_RELAXED, __HIP_MEMORY_SCOPE_AGENT);
            __hip_atomic_store(hp + 3, q3, __ATOMIC_RELAXED, __HIP_MEMORY_SCOPE_AGENT);
            if (LAYER == 1) {
                uint4 pk;
                pk.x = (hr[0] & 0xffffu) | (hr[1] << 16);
                pk.y = (hr[2] & 0xffffu) | (hr[3] << 16);
                pk.z = (hr[4] & 0xffffu) | (hr[5] << 16);
                pk.w = (hr[6] & 0xffffu) | (hr[7] << 16);
                *reinterpret_cast<uint4*>(
                    y1bf + ((size_t)t * BATCH + lane) * HID + ubase) = pk;
            }
            if (lane == 0)
                __hip_atomic_store(flags_own + (size_t)g * FSTR, tagv,
                                   __ATOMIC_RELAXED, __HIP_MEMORY_SCOPE_AGENT);
        }
    }
    // drain trailing stores before kernel end (off the recurrence path)
    asm volatile("s_waitcnt vmcnt(0)" ::: "memory");
}

__global__ __launch_bounds__(256, 1)
void lstm_fused(const u16* __restrict__ x_bf,
                const u16* __restrict__ wih0b, const u16* __restrict__ whh0b, const float* __restrict__ b0,
                const u16* __restrict__ wih1b, const u16* __restrict__ whh1b, const float* __restrict__ b1,
                unsigned* __restrict__ y0tag, unsigned* __restrict__ ring1,
                u16* __restrict__ y1bf,
                float* __restrict__ hN, float* __restrict__ cN,
                unsigned* __restrict__ ctr)
{
    __shared__ __align__(16) u16 lds_w[2][32][512];   // 64 KB (L0 uses KS=20 of 32)
    __shared__ float lds_g[BATCH][33];
    __shared__ float lds_b[2][16];
    __shared__ __align__(16) unsigned lds_h[BATCH][8];

    unsigned* flags0 = ctr;
    unsigned* flags1 = ctr + NWG_L * FSTR;

    const int wgid = blockIdx.x;
    if (wgid < NWG_L) {
        run_layer<0>(x_bf, nullptr, y0tag, nullptr,
                     nullptr, nullptr, wih0b, whh0b, b0, hN, cN,
                     flags0, flags0, wgid, lds_w, lds_g, lds_b, lds_h);
    } else {
        run_layer<1>(nullptr, y0tag, ring1, y1bf,
                     nullptr, nullptr, wih1b, whh1b, b1,
                     hN + BATCH * HID, cN + BATCH * HID,
                     flags1, flags0, wgid - NWG_L, lds_w, lds_g, lds_b, lds_h);
    }
}

// ---------------- final FC: out[32768,256] = y1[32768,512] @ fc_w[256,512]^T + b ----------
__global__ __launch_bounds__(256)
void fc_kernel(const u16* __restrict__ y1, const u16* __restrict__ fcw,
               const float* __restrict__ fcb, float* __restrict__ out)
{
    const int tid  = threadIdx.x;
    const int lane = tid & 63;
    const int wgid = blockIdx.x * 4 + (tid >> 6);  // 0..1023 waves
    const int nq   = wgid & 3;                     // 64-col block
    const int mt0  = wgid >> 2;                    // 0..255

    for (int j = 0; j < 8; ++j) {
        int mt = mt0 + j * 256;                    // M-tile 0..2047
        f32x4 acc[4] = {{0,0,0,0},{0,0,0,0},{0,0,0,0},{0,0,0,0}};
        const u16* arow = y1 + ((size_t)mt * 16 + (lane & 15)) * HID + (lane >> 4) * 8;
        #pragma unroll
        for (int ks = 0; ks < 16; ++ks) {
            short8 a = *reinterpret_cast<const short8*>(arow + ks * 32);
            #pragma unroll
            for (int nt = 0; nt < 4; ++nt) {
                const u16* brow = fcw + ((size_t)(nq * 64 + nt * 16 + (lane & 15))) * HID
                                      + ks * 32 + (lane >> 4) * 8;
                short8 b = *reinterpret_cast<const short8*>(brow);
                acc[nt] = __builtin_amdgcn_mfma_f32_16x16x32_bf16(a, b, acc[nt], 0, 0, 0);
            }
        }
        #pragma unroll
        for (int nt = 0; nt < 4; ++nt) {
            int col = nq * 64 + nt * 16 + (lane & 15);
            float bb = fcb[col];
            #pragma unroll
            for (int jj = 0; jj < 4; ++jj) {
                int row = mt * 16 + (lane >> 4) * 4 + jj;
                out[(size_t)row * OUTF + col] = acc[nt][jj] + bb;
            }
        }
    }
}

extern "C" void kernel_launch(void* const* d_in, const int* in_sizes, int n_in,
                              void* d_out, int out_size, void* d_ws, size_t ws_size,
                              hipStream_t stream)
{
    const float* x    = (const float*)d_in[0];
    const float* wih0 = (const float*)d_in[1];
    const float* whh0 = (const float*)d_in[2];
    const float* b0   = (const float*)d_in[3];
    const float* wih1 = (const float*)d_in[4];
    const float* whh1 = (const float*)d_in[5];
    const float* b1   = (const float*)d_in[6];
    const float* fcw  = (const float*)d_in[7];
    const float* fcb  = (const float*)d_in[8];
    float* out = (float*)d_out;

    const size_t flag_bytes = (size_t)2 * NWG_L * FSTR * 4;   // 16 KB

    char* ws = (char*)d_ws;
    size_t off = 0;
    unsigned* ctr = (unsigned*)ws;                    off += flag_bytes;
    u16* x_bf    = (u16*)(ws + off);                  off += (size_t)T_SEQ * BATCH * IN0 * 2;
    u16* wih0_bf = (u16*)(ws + off);                  off += (size_t)G4 * IN0 * 2;
    u16* whh0_bf = (u16*)(ws + off);                  off += (size_t)G4 * HID * 2;
    u16* wih1_bf = (u16*)(ws + off);                  off += (size_t)G4 * HID * 2;
    u16* whh1_bf = (u16*)(ws + off);                  off += (size_t)G4 * HID * 2;
    u16* fcw_bf  = (u16*)(ws + off);                  off += (size_t)OUTF * HID * 2;
    unsigned* y0tag = (unsigned*)(ws + off);          off += (size_t)T_SEQ * BATCH * HID * 4;  // 64 MB
    unsigned* ring1 = (unsigned*)(ws + off);          off += (size_t)RING * BATCH * HID * 4;   // 1 MB
    u16* y1bf    = (u16*)(ws + off);                  off += (size_t)T_SEQ * BATCH * HID * 2;  // 32 MB

    hipMemsetAsync(ctr, 0, flag_bytes, stream);

    auto conv = [&](const float* in, u16* o, int n) {
        int n4 = n / 4;
        cvt_f32_bf16<<<(n4 + 255) / 256, 256, 0, stream>>>(in, o, n4);
    };
    conv(x,    x_bf,    T_SEQ * BATCH * IN0);
    conv(wih0, wih0_bf, G4 * IN0);
    conv(whh0, whh0_bf, G4 * HID);
    conv(wih1, wih1_bf, G4 * HID);
    conv(whh1, whh1_bf, G4 * HID);
    conv(fcw,  fcw_bf,  OUTF * HID);

    float* outFC = out;
    float* hN = out + (size_t)T_SEQ * BATCH * OUTF;     // [2,B,H]
    float* cN = hN + 2 * BATCH * HID;                   // [2,B,H]

    lstm_fused<<<2 * NWG_L, 256, 0, stream>>>(x_bf, wih0_bf, whh0_bf, b0,
                                              wih1_bf, whh1_bf, b1,
                                              y0tag, ring1, y1bf, hN, cN, ctr);
    fc_kernel<<<256, 256, 0, stream>>>(y1bf, fcw_bf, fcb, outFC);
}

// Round 20
// 3779.675 us; speedup vs baseline: 1.6405x; 1.6405x over previous
//
#include <hip/hip_runtime.h>
#include <hip/hip_bf16.h>

#define T_SEQ 512
#define BATCH 64
#define IN0   128
#define HID   512
#define OUTF  256
#define G4    (4*HID)     // 2048 gate rows
#define NWG_L 64          // workgroups per layer (each owns 8 hidden units)
#define FSTR  32          // u32s between flags -> one 128B line per producer
#define NTHR  320         // 4 compute waves + 1 publisher wave

typedef __attribute__((ext_vector_type(8))) short short8;   // 8 bf16 (MFMA A/B frag)
typedef __attribute__((ext_vector_type(4))) float f32x4;    // MFMA C/D frag
typedef unsigned short u16;
typedef unsigned long long u64;

__device__ __forceinline__ float sigmoidf_(float x) { return 1.f / (1.f + __expf(-x)); }
__device__ __forceinline__ float tanhf_(float x)    { return 1.f - 2.f / (1.f + __expf(2.f * x)); }

__device__ __forceinline__ u16 f2bf(float f) {
    union { float f; unsigned u; } a; a.f = f;
    unsigned u = a.u;
    return (u16)((u + 0x7fffu + ((u >> 16) & 1u)) >> 16);   // RNE
}

// ONE combined poll per step (R18): lane l watches own-flag[l] (target to,
// 0=skip) and (L1) dep-flag[l] (target td). Producers publish flag t during
// body t (pipelined), so a short wait is possible here — backoff retained.
template<int LAYER>
__device__ __forceinline__ void poll_all(const unsigned* fo, const unsigned* fd,
                                         int lane, unsigned to, unsigned td) {
    const unsigned* po = fo + (size_t)lane * FSTR;
    const unsigned* pd = fd + (size_t)lane * FSTR;
    unsigned it = 0;
    for (;;) {
        bool ok = true;
        if (to)
            ok = __hip_atomic_load(po, __ATOMIC_RELAXED, __HIP_MEMORY_SCOPE_AGENT) >= to;
        if (LAYER == 1)
            ok = ok && (__hip_atomic_load(pd, __ATOMIC_RELAXED, __HIP_MEMORY_SCOPE_AGENT) >= td);
        if (__all((int)ok)) return;
        if (it < 8) __builtin_amdgcn_s_sleep(1);
        else        __builtin_amdgcn_s_sleep(8);
        if ((++it & 1023u) == 0u)
            (void)__hip_atomic_load(po, __ATOMIC_ACQUIRE, __HIP_MEMORY_SCOPE_AGENT);
    }
}

// ---------------- f32 -> bf16 conversion ----------------
__global__ void cvt_f32_bf16(const float* __restrict__ in, u16* __restrict__ out, int n4) {
    int i = blockIdx.x * blockDim.x + threadIdx.x;
    if (i < n4) {
        float4 v = reinterpret_cast<const float4*>(in)[i];
        ushort4 o;
        o.x = f2bf(v.x); o.y = f2bf(v.y); o.z = f2bf(v.z); o.w = f2bf(v.w);
        reinterpret_cast<ushort4*>(out)[i] = o;
    }
}

// ---------------- fused pipelined 2-layer LSTM ----------------
// WG g in [0,64): layer 0, owns hidden units [8g, 8g+8) -> 32 gate rows as 2
// MFMA col-tiles. WG 64+g: layer 1, same ownership. 5 waves per WG:
//   waves 0-3: poll -> merged branch-free A-frag loads -> all MFMAs ->
//              exchange -> cell -> lds_h[t&1]   (ONE load-latency exposure)
//   wave 4   : publishes step t-1 from lds_h[(t-1)&1] DURING step t's compute
//              (stores -> vmcnt ack -> flag) — ack is off the compute path.
template<int LAYER>
__device__ __forceinline__ void run_layer(
    const u16* __restrict__ asrc,   // L0: x_bf [T,B,128]; L1: y0 [T,B,512]
    const u16* __restrict__ wihb, const u16* __restrict__ whhb,
    const float* __restrict__ bias,
    u16* __restrict__ ybuf,         // own-layer h/y storage [T,B,512]
    float* __restrict__ hNout, float* __restrict__ cNout,
    unsigned* flags_own, unsigned* flags_dep, int g,
    u16 (*lds_w)[32][512], float (*lds_g)[33], float (*lds_b)[16],
    unsigned (*lds_h)[BATCH][4])
{
    constexpr int KIN = (LAYER == 0) ? IN0 : HID;
    constexpr int KS1 = KIN / 32;        // input-part K slices
    constexpr int KS  = KS1 + 16;        // + recurrent K slices

    const int tid  = threadIdx.x;
    const int lane = tid & 63;
    const int w    = tid >> 6;           // 0..3 compute (batch rows 16w..), 4 publisher
    const int ubase = 8 * g;

    // ---- pack weights into LDS in MFMA B-frag order (2 col-tiles) ----
    for (int idx = tid; idx < 2 * KS * 64; idx += NTHR) {
        int nt  = (idx >= KS * 64) ? 1 : 0;
        int rem = idx - nt * KS * 64;
        int ks = rem >> 6, s = rem & 63, q = s & 15, kq = s >> 4;
        int r = (q >> 2) * HID + ubase + 4 * nt + (q & 3);   // global gate row
        const u16* src = (ks < KS1)
            ? wihb + (size_t)r * KIN + (size_t)ks * 32 + kq * 8
            : whhb + (size_t)r * HID + (size_t)(ks - KS1) * 32 + kq * 8;
        *reinterpret_cast<uint4*>(&lds_w[nt][ks][s * 8]) =
            *reinterpret_cast<const uint4*>(src);
    }
    if (tid < 32) {
        int nt = tid >> 4, q = tid & 15;
        lds_b[nt][q] = bias[(q >> 2) * HID + ubase + 4 * nt + (q & 3)];
    }
    __syncthreads();

    const int pb  = tid & 63;   // pointwise: batch index
    const int pu2 = tid >> 6;   // pointwise: unit-pair index (0..3; wave4 skips)
    float c0 = 0.f, c1 = 0.f;

    const int arow = 16 * w + (lane & 15);   // valid for w<4
    const int koff = (lane >> 4) * 8;

    for (int t = 0; t < T_SEQ; ++t) {
        f32x4 ac0[4] = {{0,0,0,0},{0,0,0,0},{0,0,0,0},{0,0,0,0}};
        f32x4 ac1[4] = {{0,0,0,0},{0,0,0,0},{0,0,0,0},{0,0,0,0}};

        if (w == 4) {
            // ---- publisher: step t-1's h block (concurrent with compute) ----
            if (t > 0) {
                const int s = t - 1;
                const unsigned* hr = lds_h[s & 1][lane];
                u64 q0 = (u64)hr[0] | ((u64)hr[1] << 32);
                u64 q1 = (u64)hr[2] | ((u64)hr[3] << 32);
                u64* yp = reinterpret_cast<u64*>(
                    ybuf + ((size_t)s * BATCH + lane) * HID + ubase);
                __hip_atomic_store(yp + 0, q0, __ATOMIC_RELAXED, __HIP_MEMORY_SCOPE_AGENT);
                __hip_atomic_store(yp + 1, q1, __ATOMIC_RELAXED, __HIP_MEMORY_SCOPE_AGENT);
                asm volatile("s_waitcnt vmcnt(0)" ::: "memory");
                if (lane == 0)
                    __hip_atomic_store(flags_own + (size_t)g * FSTR, (unsigned)t,
                                       __ATOMIC_RELAXED, __HIP_MEMORY_SCOPE_AGENT);
            }
        } else {
            // ---- compute: L0 x-GEMM first (no dep), then one poll, then
            // ALL remaining loads branch-free, then all MFMAs ----
            if (LAYER == 0) {
                const u16* ap = asrc + ((size_t)t * BATCH + arow) * KIN + koff;
                short8 a[KS1];
                #pragma unroll
                for (int j = 0; j < KS1; ++j)
                    a[j] = *reinterpret_cast<const short8*>(ap + j * 32);
                #pragma unroll
                for (int j = 0; j < KS1; ++j) {
                    ac0[j & 3] = __builtin_amdgcn_mfma_f32_16x16x32_bf16(
                        a[j], *reinterpret_cast<const short8*>(&lds_w[0][j][lane * 8]), ac0[j & 3], 0, 0, 0);
                    ac1[j & 3] = __builtin_amdgcn_mfma_f32_16x16x32_bf16(
                        a[j], *reinterpret_cast<const short8*>(&lds_w[1][j][lane * 8]), ac1[j & 3], 0, 0, 0);
                }
            }

            if (LAYER == 1 || t > 0)
                poll_all<LAYER>(flags_own, flags_dep, lane, (unsigned)t, (unsigned)(t + 1));

            if (LAYER == 1) {
                const u16* ap = asrc + ((size_t)t * BATCH + arow) * HID + koff;
                short8 ay[16];
                #pragma unroll
                for (int j = 0; j < 16; ++j)
                    ay[j] = *reinterpret_cast<const short8*>(ap + j * 32);
                if (t > 0) {
                    const u16* hp = ybuf + ((size_t)(t - 1) * BATCH + arow) * HID + koff;
                    short8 ah[16];
                    #pragma unroll
                    for (int j = 0; j < 16; ++j)
                        ah[j] = *reinterpret_cast<const short8*>(hp + j * 32);
                    #pragma unroll
                    for (int j = 0; j < 16; ++j) {
                        ac0[j & 3] = __builtin_amdgcn_mfma_f32_16x16x32_bf16(
                            ay[j], *reinterpret_cast<const short8*>(&lds_w[0][j][lane * 8]), ac0[j & 3], 0, 0, 0);
                        ac1[j & 3] = __builtin_amdgcn_mfma_f32_16x16x32_bf16(
                            ay[j], *reinterpret_cast<const short8*>(&lds_w[1][j][lane * 8]), ac1[j & 3], 0, 0, 0);
                        ac0[j & 3] = __builtin_amdgcn_mfma_f32_16x16x32_bf16(
                            ah[j], *reinterpret_cast<const short8*>(&lds_w[0][KS1 + j][lane * 8]), ac0[j & 3], 0, 0, 0);
                        ac1[j & 3] = __builtin_amdgcn_mfma_f32_16x16x32_bf16(
                            ah[j], *reinterpret_cast<const short8*>(&lds_w[1][KS1 + j][lane * 8]), ac1[j & 3], 0, 0, 0);
                    }
                } else {
                    #pragma unroll
                    for (int j = 0; j < 16; ++j) {
                        ac0[j & 3] = __builtin_amdgcn_mfma_f32_16x16x32_bf16(
                            ay[j], *reinterpret_cast<const short8*>(&lds_w[0][j][lane * 8]), ac0[j & 3], 0, 0, 0);
                        ac1[j & 3] = __builtin_amdgcn_mfma_f32_16x16x32_bf16(
                            ay[j], *reinterpret_cast<const short8*>(&lds_w[1][j][lane * 8]), ac1[j & 3], 0, 0, 0);
                    }
                }
            } else if (t > 0) {
                const u16* hp = ybuf + ((size_t)(t - 1) * BATCH + arow) * HID + koff;
                short8 ah[16];
                #pragma unroll
                for (int j = 0; j < 16; ++j)
                    ah[j] = *reinterpret_cast<const short8*>(hp + j * 32);
                #pragma unroll
                for (int j = 0; j < 16; ++j) {
                    ac0[j & 3] = __builtin_amdgcn_mfma_f32_16x16x32_bf16(
                        ah[j], *reinterpret_cast<const short8*>(&lds_w[0][KS1 + j][lane * 8]), ac0[j & 3], 0, 0, 0);
                    ac1[j & 3] = __builtin_amdgcn_mfma_f32_16x16x32_bf16(
                        ah[j], *reinterpret_cast<const short8*>(&lds_w[1][KS1 + j][lane * 8]), ac1[j & 3], 0, 0, 0);
                }
            }

            f32x4 s0 = (ac0[0] + ac0[1]) + (ac0[2] + ac0[3]);
            f32x4 s1 = (ac1[0] + ac1[1]) + (ac1[2] + ac1[3]);
            // D frag: row = 16w + (lane>>4)*4 + j (batch), col = lane&15 (q)
            #pragma unroll
            for (int j = 0; j < 4; ++j) {
                int row = 16 * w + (lane >> 4) * 4 + j;
                lds_g[row][lane & 15]        = s0[j];
                lds_g[row][16 + (lane & 15)] = s1[j];
            }
        }
        __syncthreads();   // lds_g ready; publisher done with lds_h[(t-1)&1]

        if (w < 4) {
            // ---- cell update (f32): thread (pb,pu2) owns units 2pu2, 2pu2+1 ----
            const int nt = pu2 >> 1;
            const int dq = (2 * pu2) & 3;
            const float* gr = &lds_g[pb][nt * 16];
            const float* br = lds_b[nt];
            float gi0 = sigmoidf_(gr[dq]      + br[dq]);
            float gf0 = sigmoidf_(gr[4 + dq]  + br[4 + dq]);
            float gg0 = tanhf_(   gr[8 + dq]  + br[8 + dq]);
            float go0 = sigmoidf_(gr[12 + dq] + br[12 + dq]);
            c0 = gf0 * c0 + gi0 * gg0;
            float h0v = go0 * tanhf_(c0);
            float gi1 = sigmoidf_(gr[dq + 1]      + br[dq + 1]);
            float gf1 = sigmoidf_(gr[4 + dq + 1]  + br[4 + dq + 1]);
            float gg1 = tanhf_(   gr[8 + dq + 1]  + br[8 + dq + 1]);
            float go1 = sigmoidf_(gr[12 + dq + 1] + br[12 + dq + 1]);
            c1 = gf1 * c1 + gi1 * gg1;
            float h1v = go1 * tanhf_(c1);

            lds_h[t & 1][pb][pu2] = (unsigned)f2bf(h0v) | ((unsigned)f2bf(h1v) << 16);

            if (t == T_SEQ - 1) {
                const int u0 = ubase + 4 * nt + dq, u1 = u0 + 1;
                hNout[pb * HID + u0] = h0v;
                hNout[pb * HID + u1] = h1v;
                cNout[pb * HID + u0] = c0;
                cNout[pb * HID + u1] = c1;
            }
        }
        __syncthreads();   // lds_h[t&1] complete -> publisher may take it next iter
    }

    // ---- epilogue: publish the final step ----
    if (w == 4) {
        const int s = T_SEQ - 1;
        const unsigned* hr = lds_h[s & 1][lane];
        u64 q0 = (u64)hr[0] | ((u64)hr[1] << 32);
        u64 q1 = (u64)hr[2] | ((u64)hr[3] << 32);
        u64* yp = reinterpret_cast<u64*>(
            ybuf + ((size_t)s * BATCH + lane) * HID + ubase);
        __hip_atomic_store(yp + 0, q0, __ATOMIC_RELAXED, __HIP_MEMORY_SCOPE_AGENT);
        __hip_atomic_store(yp + 1, q1, __ATOMIC_RELAXED, __HIP_MEMORY_SCOPE_AGENT);
        asm volatile("s_waitcnt vmcnt(0)" ::: "memory");
        if (lane == 0)
            __hip_atomic_store(flags_own + (size_t)g * FSTR, (unsigned)T_SEQ,
                               __ATOMIC_RELAXED, __HIP_MEMORY_SCOPE_AGENT);
    }
}

__global__ __launch_bounds__(NTHR, 1)
void lstm_fused(const u16* __restrict__ x_bf,
                const u16* __restrict__ wih0, const u16* __restrict__ whh0, const float* __restrict__ b0,
                const u16* __restrict__ wih1, const u16* __restrict__ whh1, const float* __restrict__ b1,
                u16* __restrict__ y0, u16* __restrict__ y1,
                float* __restrict__ hN, float* __restrict__ cN,
                unsigned* __restrict__ ctr)
{
    __shared__ __align__(16) u16 lds_w[2][32][512];   // 64 KB (L0 uses KS=20 of 32)
    __shared__ float lds_g[BATCH][33];
    __shared__ float lds_b[2][16];
    __shared__ __align__(16) unsigned lds_h[2][BATCH][4];

    unsigned* flags0 = ctr;
    unsigned* flags1 = ctr + NWG_L * FSTR;

    const int wgid = blockIdx.x;
    if (wgid < NWG_L) {
        run_layer<0>(x_bf, wih0, whh0, b0, y0, hN, cN,
                     flags0, flags0, wgid, lds_w, lds_g, lds_b, lds_h);
    } else {
        run_layer<1>(y0, wih1, whh1, b1, y1, hN + BATCH * HID, cN + BATCH * HID,
                     flags1, flags0, wgid - NWG_L, lds_w, lds_g, lds_b, lds_h);
    }
}

// ---------------- final FC: out[32768,256] = y1[32768,512] @ fc_w[256,512]^T + b ----------
__global__ __launch_bounds__(256)
void fc_kernel(const u16* __restrict__ y1, const u16* __restrict__ fcw,
               const float* __restrict__ fcb, float* __restrict__ out)
{
    const int tid  = threadIdx.x;
    const int lane = tid & 63;
    const int wgid = blockIdx.x * 4 + (tid >> 6);  // 0..1023 waves
    const int nq   = wgid & 3;                     // 64-col block
    const int mt0  = wgid >> 2;                    // 0..255

    for (int j = 0; j < 8; ++j) {
        int mt = mt0 + j * 256;                    // M-tile 0..2047
        f32x4 acc[4] = {{0,0,0,0},{0,0,0,0},{0,0,0,0},{0,0,0,0}};
        const u16* arow = y1 + ((size_t)mt * 16 + (lane & 15)) * HID + (lane >> 4) * 8;
        #pragma unroll
        for (int ks = 0; ks < 16; ++ks) {
            short8 a = *reinterpret_cast<const short8*>(arow + ks * 32);
            #pragma unroll
            for (int nt = 0; nt < 4; ++nt) {
                const u16* brow = fcw + ((size_t)(nq * 64 + nt * 16 + (lane & 15))) * HID
                                      + ks * 32 + (lane >> 4) * 8;
                short8 b = *reinterpret_cast<const short8*>(brow);
                acc[nt] = __builtin_amdgcn_mfma_f32_16x16x32_bf16(a, b, acc[nt], 0, 0, 0);
            }
        }
        #pragma unroll
        for (int nt = 0; nt < 4; ++nt) {
            int col = nq * 64 + nt * 16 + (lane & 15);
            float bb = fcb[col];
            #pragma unroll
            for (int jj = 0; jj < 4; ++jj) {
                int row = mt * 16 + (lane >> 4) * 4 + jj;
                out[(size_t)row * OUTF + col] = acc[nt][jj] + bb;
            }
        }
    }
}

extern "C" void kernel_launch(void* const* d_in, const int* in_sizes, int n_in,
                              void* d_out, int out_size, void* d_ws, size_t ws_size,
                              hipStream_t stream)
{
    const float* x    = (const float*)d_in[0];
    const float* wih0 = (const float*)d_in[1];
    const float* whh0 = (const float*)d_in[2];
    const float* b0   = (const float*)d_in[3];
    const float* wih1 = (const float*)d_in[4];
    const float* whh1 = (const float*)d_in[5];
    const float* b1   = (const float*)d_in[6];
    const float* fcw  = (const float*)d_in[7];
    const float* fcb  = (const float*)d_in[8];
    float* out = (float*)d_out;

    const size_t flag_bytes = (size_t)2 * NWG_L * FSTR * 4;   // 16 KB

    char* ws = (char*)d_ws;
    size_t off = 0;
    unsigned* ctr = (unsigned*)ws;                    off += flag_bytes;
    u16* x_bf    = (u16*)(ws + off);                  off += (size_t)T_SEQ * BATCH * IN0 * 2;
    u16* wih0_bf = (u16*)(ws + off);                  off += (size_t)G4 * IN0 * 2;
    u16* whh0_bf = (u16*)(ws + off);                  off += (size_t)G4 * HID * 2;
    u16* wih1_bf = (u16*)(ws + off);                  off += (size_t)G4 * HID * 2;
    u16* whh1_bf = (u16*)(ws + off);                  off += (size_t)G4 * HID * 2;
    u16* fcw_bf  = (u16*)(ws + off);                  off += (size_t)OUTF * HID * 2;
    u16* y0      = (u16*)(ws + off);                  off += (size_t)T_SEQ * BATCH * HID * 2;
    u16* y1      = (u16*)(ws + off);                  off += (size_t)T_SEQ * BATCH * HID * 2;

    hipMemsetAsync(ctr, 0, flag_bytes, stream);

    auto conv = [&](const float* in, u16* o, int n) {
        int n4 = n / 4;
        cvt_f32_bf16<<<(n4 + 255) / 256, 256, 0, stream>>>(in, o, n4);
    };
    conv(x,    x_bf,    T_SEQ * BATCH * IN0);
    conv(wih0, wih0_bf, G4 * IN0);
    conv(whh0, whh0_bf, G4 * HID);
    conv(wih1, wih1_bf, G4 * HID);
    conv(whh1, whh1_bf, G4 * HID);
    conv(fcw,  fcw_bf,  OUTF * HID);

    float* outFC = out;
    float* hN = out + (size_t)T_SEQ * BATCH * OUTF;     // [2,B,H]
    float* cN = hN + 2 * BATCH * HID;                   // [2,B,H]

    lstm_fused<<<2 * NWG_L, NTHR, 0, stream>>>(x_bf, wih0_bf, whh0_bf, b0,
                                               wih1_bf, whh1_bf, b1,
                                               y0, y1, hN, cN, ctr);
    fc_kernel<<<256, 256, 0, stream>>>(y1, fcw_bf, fcb, outFC);
}

// Round 21
// 3281.787 us; speedup vs baseline: 1.8894x; 1.1517x over previous
//
#include <hip/hip_runtime.h>
#include <hip/hip_bf16.h>

#define T_SEQ 512
#define BATCH 64
#define IN0   128
#define HID   512
#define OUTF  256
#define G4    (4*HID)     // 2048 gate rows
#define NWG_L 64          // workgroups per layer (each owns 8 hidden units)
#define FSTR  32          // u32s between flags -> one 128B line per producer

typedef __attribute__((ext_vector_type(8))) short short8;   // 8 bf16 (MFMA A/B frag)
typedef __attribute__((ext_vector_type(4))) float f32x4;    // MFMA C/D frag
typedef unsigned short u16;
typedef unsigned long long u64;

__device__ __forceinline__ float sigmoidf_(float x) { return 1.f / (1.f + __expf(-x)); }
__device__ __forceinline__ float tanhf_(float x)    { return 1.f - 2.f / (1.f + __expf(2.f * x)); }

__device__ __forceinline__ u16 f2bf(float f) {
    union { float f; unsigned u; } a; a.f = f;
    unsigned u = a.u;
    return (u16)((u + 0x7fffu + ((u >> 16) & 1u)) >> 16);   // RNE
}

// Groupwise poll with backoff (R13 best-known): wait for producers
// [16*grp, 16*grp+16) >= tgt. Lane l watches flags[(16*grp + (l&15)) * FSTR].
__device__ __forceinline__ void poll_grp(const unsigned* flags, int lane, int grp, unsigned tgt) {
    const unsigned* p = flags + (size_t)(grp * 16 + (lane & 15)) * FSTR;
    unsigned it = 0;
    for (;;) {
        unsigned v = __hip_atomic_load(p, __ATOMIC_RELAXED, __HIP_MEMORY_SCOPE_AGENT);
        if (__all((int)(v >= tgt))) return;
        if (it < 6) __builtin_amdgcn_s_sleep(1);
        else        __builtin_amdgcn_s_sleep(16);
        if ((++it & 1023u) == 0u)
            (void)__hip_atomic_load(p, __ATOMIC_ACQUIRE, __HIP_MEMORY_SCOPE_AGENT);
    }
}

// ---------------- f32 -> bf16 conversion ----------------
__global__ void cvt_f32_bf16(const float* __restrict__ in, u16* __restrict__ out, int n4) {
    int i = blockIdx.x * blockDim.x + threadIdx.x;
    if (i < n4) {
        float4 v = reinterpret_cast<const float4*>(in)[i];
        ushort4 o;
        o.x = f2bf(v.x); o.y = f2bf(v.y); o.z = f2bf(v.z); o.w = f2bf(v.w);
        reinterpret_cast<ushort4*>(out)[i] = o;
    }
}

// ---------------- fused pipelined 2-layer LSTM ----------------
// WG g in [0,64): layer 0, owns hidden units [8g, 8g+8) -> 32 gate rows as 2
// MFMA col-tiles. WG 64+g: layer 1, same ownership.
// flags[g*FSTR] = #steps completed by WG g of that layer.
// Waits are groupwise and self-paced per wave: K-slice group grp (4 slices)
// depends only on producers [16grp,16grp+16); poll -> load 4 slices -> MFMA.
// Publish: wave 0 stores the WG's 1KB h-block, own-ack vmcnt, lane 0 flag.
// This structure measured 3321us = 6.49us/step; 15 protocol/structure
// variants (R4-R20) bracket the per-step cross-CU handoff at ~6.5us, which
// x512 serial steps IS the measured duration — latency-bound plateau.
template<int LAYER>
__device__ __forceinline__ void run_layer(
    const u16* __restrict__ asrc,   // L0: x_bf [T,B,128]; L1: y0 [T,B,512]
    const u16* __restrict__ wih, const u16* __restrict__ whh,
    const float* __restrict__ bias,
    u16* __restrict__ ybuf,         // own-layer h/y storage [T,B,512]
    float* __restrict__ hNout, float* __restrict__ cNout,
    unsigned* flags_own, unsigned* flags_dep, int g,
    u16 (*lds_w)[32][512], float (*lds_g)[33], float (*lds_b)[16],
    unsigned (*lds_h)[4])
{
    constexpr int KIN = (LAYER == 0) ? IN0 : HID;
    constexpr int KS1 = KIN / 32;        // input-part K slices
    constexpr int KS  = KS1 + 16;        // + recurrent K slices

    const int tid  = threadIdx.x;
    const int lane = tid & 63;
    const int w    = tid >> 6;           // wave id -> batch rows 16w..16w+15
    const int ubase = 8 * g;

    // ---- pack weights into LDS in MFMA B-frag order (2 col-tiles) ----
    for (int idx = tid; idx < 2 * KS * 64; idx += 256) {
        int nt  = (idx >= KS * 64) ? 1 : 0;
        int rem = idx - nt * KS * 64;
        int ks = rem >> 6, s = rem & 63, q = s & 15, kq = s >> 4;
        int r = (q >> 2) * HID + ubase + 4 * nt + (q & 3);   // global gate row
        const u16* src = (ks < KS1)
            ? wih + (size_t)r * KIN + (size_t)ks * 32 + kq * 8
            : whh + (size_t)r * HID + (size_t)(ks - KS1) * 32 + kq * 8;
        *reinterpret_cast<uint4*>(&lds_w[nt][ks][s * 8]) =
            *reinterpret_cast<const uint4*>(src);
    }
    if (tid < 32) {
        int nt = tid >> 4, q = tid & 15;
        lds_b[nt][q] = bias[(q >> 2) * HID + ubase + 4 * nt + (q & 3)];
    }
    __syncthreads();

    const int pb  = tid & 63;   // pointwise: batch index
    const int pu2 = tid >> 6;   // pointwise: unit-pair index (0..3)
    float c0 = 0.f, c1 = 0.f;

    const int arow = 16 * w + (lane & 15);
    const int koff = (lane >> 4) * 8;

    for (int t = 0; t < T_SEQ; ++t) {
        f32x4 ac0[4] = {{0,0,0,0},{0,0,0,0},{0,0,0,0},{0,0,0,0}};
        f32x4 ac1[4] = {{0,0,0,0},{0,0,0,0},{0,0,0,0},{0,0,0,0}};

        // ---- input contribution ----
        if (LAYER == 0) {
            // x[t]: no dependency
            const u16* ap = asrc + ((size_t)t * BATCH + arow) * KIN + koff;
            short8 a[KS1];
            #pragma unroll
            for (int j = 0; j < KS1; ++j)
                a[j] = *reinterpret_cast<const short8*>(ap + j * 32);
            #pragma unroll
            for (int j = 0; j < KS1; ++j) {
                ac0[j & 3] = __builtin_amdgcn_mfma_f32_16x16x32_bf16(
                    a[j], *reinterpret_cast<const short8*>(&lds_w[0][j][lane * 8]), ac0[j & 3], 0, 0, 0);
                ac1[j & 3] = __builtin_amdgcn_mfma_f32_16x16x32_bf16(
                    a[j], *reinterpret_cast<const short8*>(&lds_w[1][j][lane * 8]), ac1[j & 3], 0, 0, 0);
            }
        } else {
            // y0[t]: groupwise (L0 runs ahead -> polls usually hit first try)
            const u16* ap = asrc + ((size_t)t * BATCH + arow) * HID + koff;
            for (int grp = 0; grp < 4; ++grp) {
                poll_grp(flags_dep, lane, grp, (unsigned)(t + 1));
                #pragma unroll
                for (int j = 0; j < 4; ++j) {
                    int ks = grp * 4 + j;
                    short8 a = *reinterpret_cast<const short8*>(ap + ks * 32);
                    ac0[j] = __builtin_amdgcn_mfma_f32_16x16x32_bf16(
                        a, *reinterpret_cast<const short8*>(&lds_w[0][ks][lane * 8]), ac0[j], 0, 0, 0);
                    ac1[j] = __builtin_amdgcn_mfma_f32_16x16x32_bf16(
                        a, *reinterpret_cast<const short8*>(&lds_w[1][ks][lane * 8]), ac1[j], 0, 0, 0);
                }
            }
        }

        // ---- recurrent contribution h[t-1]: groupwise self-paced ----
        if (t > 0) {
            const u16* hp = ybuf + ((size_t)(t - 1) * BATCH + arow) * HID + koff;
            for (int grp = 0; grp < 4; ++grp) {
                poll_grp(flags_own, lane, grp, (unsigned)t);
                #pragma unroll
                for (int j = 0; j < 4; ++j) {
                    int ks = grp * 4 + j;
                    short8 a = *reinterpret_cast<const short8*>(hp + ks * 32);
                    ac0[j] = __builtin_amdgcn_mfma_f32_16x16x32_bf16(
                        a, *reinterpret_cast<const short8*>(&lds_w[0][KS1 + ks][lane * 8]), ac0[j], 0, 0, 0);
                    ac1[j] = __builtin_amdgcn_mfma_f32_16x16x32_bf16(
                        a, *reinterpret_cast<const short8*>(&lds_w[1][KS1 + ks][lane * 8]), ac1[j], 0, 0, 0);
                }
            }
        }

        f32x4 s0 = (ac0[0] + ac0[1]) + (ac0[2] + ac0[3]);
        f32x4 s1 = (ac1[0] + ac1[1]) + (ac1[2] + ac1[3]);
        // D frag: row = 16w + (lane>>4)*4 + j (batch), col = lane&15 (q)
        #pragma unroll
        for (int j = 0; j < 4; ++j) {
            int row = 16 * w + (lane >> 4) * 4 + j;
            lds_g[row][lane & 15]        = s0[j];
            lds_g[row][16 + (lane & 15)] = s1[j];
        }
        __syncthreads();

        // pointwise cell update (f32): thread (pb,pu2) owns units 2pu2, 2pu2+1
        {
            const int nt = pu2 >> 1;
            const int dq = (2 * pu2) & 3;
            const float* gr = &lds_g[pb][nt * 16];
            const float* br = lds_b[nt];
            float gi0 = sigmoidf_(gr[dq]      + br[dq]);
            float gf0 = sigmoidf_(gr[4 + dq]  + br[4 + dq]);
            float gg0 = tanhf_(   gr[8 + dq]  + br[8 + dq]);
            float go0 = sigmoidf_(gr[12 + dq] + br[12 + dq]);
            c0 = gf0 * c0 + gi0 * gg0;
            float h0v = go0 * tanhf_(c0);
            float gi1 = sigmoidf_(gr[dq + 1]      + br[dq + 1]);
            float gf1 = sigmoidf_(gr[4 + dq + 1]  + br[4 + dq + 1]);
            float gg1 = tanhf_(   gr[8 + dq + 1]  + br[8 + dq + 1]);
            float go1 = sigmoidf_(gr[12 + dq + 1] + br[12 + dq + 1]);
            c1 = gf1 * c1 + gi1 * gg1;
            float h1v = go1 * tanhf_(c1);

            lds_h[pb][pu2] = (unsigned)f2bf(h0v) | ((unsigned)f2bf(h1v) << 16);

            if (t == T_SEQ - 1) {
                const int u0 = ubase + 4 * nt + dq, u1 = u0 + 1;
                hNout[pb * HID + u0] = h0v;
                hNout[pb * HID + u1] = h1v;
                cNout[pb * HID + u0] = c0;
                cNout[pb * HID + u1] = c1;
            }
        }
        __syncthreads();

        // slim publish (R6): wave 0 stores the WG's whole 1KB block (16B/lane
        // as 2x u64 agent stores), waits only its own acks, then lane 0
        // raises the flag. Waves 1-3 run ahead into step t+1.
        if (w == 0) {
            uint4 hv = *reinterpret_cast<const uint4*>(&lds_h[lane][0]);
            u64 q0 = (u64)hv.x | ((u64)hv.y << 32);
            u64 q1 = (u64)hv.z | ((u64)hv.w << 32);
            u64* yp = reinterpret_cast<u64*>(
                ybuf + ((size_t)t * BATCH + lane) * HID + ubase);
            __hip_atomic_store(yp + 0, q0, __ATOMIC_RELAXED, __HIP_MEMORY_SCOPE_AGENT);
            __hip_atomic_store(yp + 1, q1, __ATOMIC_RELAXED, __HIP_MEMORY_SCOPE_AGENT);
            asm volatile("s_waitcnt vmcnt(0)" ::: "memory");
            if (lane == 0)
                __hip_atomic_store(flags_own + (size_t)g * FSTR, (unsigned)(t + 1),
                                   __ATOMIC_RELAXED, __HIP_MEMORY_SCOPE_AGENT);
        }
    }
}

__global__ __launch_bounds__(256, 1)
void lstm_fused(const u16* __restrict__ x_bf,
                const u16* __restrict__ wih0, const u16* __restrict__ whh0, const float* __restrict__ b0,
                const u16* __restrict__ wih1, const u16* __restrict__ whh1, const float* __restrict__ b1,
                u16* __restrict__ y0, u16* __restrict__ y1,
                float* __restrict__ hN, float* __restrict__ cN,
                unsigned* __restrict__ ctr)
{
    __shared__ __align__(16) u16 lds_w[2][32][512];   // 64 KB (L0 uses KS=20 of 32)
    __shared__ float lds_g[BATCH][33];
    __shared__ float lds_b[2][16];
    __shared__ __align__(16) unsigned lds_h[BATCH][4];

    unsigned* flags0 = ctr;
    unsigned* flags1 = ctr + NWG_L * FSTR;

    const int wgid = blockIdx.x;
    if (wgid < NWG_L) {
        run_layer<0>(x_bf, wih0, whh0, b0, y0, hN, cN,
                     flags0, flags0, wgid, lds_w, lds_g, lds_b, lds_h);
    } else {
        run_layer<1>(y0, wih1, whh1, b1, y1, hN + BATCH * HID, cN + BATCH * HID,
                     flags1, flags0, wgid - NWG_L, lds_w, lds_g, lds_b, lds_h);
    }
}

// ---------------- final FC: out[32768,256] = y1[32768,512] @ fc_w[256,512]^T + b ----------
__global__ __launch_bounds__(256)
void fc_kernel(const u16* __restrict__ y1, const u16* __restrict__ fcw,
               const float* __restrict__ fcb, float* __restrict__ out)
{
    const int tid  = threadIdx.x;
    const int lane = tid & 63;
    const int wgid = blockIdx.x * 4 + (tid >> 6);  // 0..1023 waves
    const int nq   = wgid & 3;                     // 64-col block
    const int mt0  = wgid >> 2;                    // 0..255

    for (int j = 0; j < 8; ++j) {
        int mt = mt0 + j * 256;                    // M-tile 0..2047
        f32x4 acc[4] = {{0,0,0,0},{0,0,0,0},{0,0,0,0},{0,0,0,0}};
        const u16* arow = y1 + ((size_t)mt * 16 + (lane & 15)) * HID + (lane >> 4) * 8;
        #pragma unroll
        for (int ks = 0; ks < 16; ++ks) {
            short8 a = *reinterpret_cast<const short8*>(arow + ks * 32);
            #pragma unroll
            for (int nt = 0; nt < 4; ++nt) {
                const u16* brow = fcw + ((size_t)(nq * 64 + nt * 16 + (lane & 15))) * HID
                                      + ks * 32 + (lane >> 4) * 8;
                short8 b = *reinterpret_cast<const short8*>(brow);
                acc[nt] = __builtin_amdgcn_mfma_f32_16x16x32_bf16(a, b, acc[nt], 0, 0, 0);
            }
        }
        #pragma unroll
        for (int nt = 0; nt < 4; ++nt) {
            int col = nq * 64 + nt * 16 + (lane & 15);
            float bb = fcb[col];
            #pragma unroll
            for (int jj = 0; jj < 4; ++jj) {
                int row = mt * 16 + (lane >> 4) * 4 + jj;
                out[(size_t)row * OUTF + col] = acc[nt][jj] + bb;
            }
        }
    }
}

extern "C" void kernel_launch(void* const* d_in, const int* in_sizes, int n_in,
                              void* d_out, int out_size, void* d_ws, size_t ws_size,
                              hipStream_t stream)
{
    const float* x    = (const float*)d_in[0];
    const float* wih0 = (const float*)d_in[1];
    const float* whh0 = (const float*)d_in[2];
    const float* b0   = (const float*)d_in[3];
    const float* wih1 = (const float*)d_in[4];
    const float* whh1 = (const float*)d_in[5];
    const float* b1   = (const float*)d_in[6];
    const float* fcw  = (const float*)d_in[7];
    const float* fcb  = (const float*)d_in[8];
    float* out = (float*)d_out;

    const size_t flag_bytes = (size_t)2 * NWG_L * FSTR * 4;   // 16 KB

    char* ws = (char*)d_ws;
    size_t off = 0;
    unsigned* ctr = (unsigned*)ws;                    off += flag_bytes;
    u16* x_bf    = (u16*)(ws + off);                  off += (size_t)T_SEQ * BATCH * IN0 * 2;
    u16* wih0_bf = (u16*)(ws + off);                  off += (size_t)G4 * IN0 * 2;
    u16* whh0_bf = (u16*)(ws + off);                  off += (size_t)G4 * HID * 2;
    u16* wih1_bf = (u16*)(ws + off);                  off += (size_t)G4 * HID * 2;
    u16* whh1_bf = (u16*)(ws + off);                  off += (size_t)G4 * HID * 2;
    u16* fcw_bf  = (u16*)(ws + off);                  off += (size_t)OUTF * HID * 2;
    u16* y0      = (u16*)(ws + off);                  off += (size_t)T_SEQ * BATCH * HID * 2;
    u16* y1      = (u16*)(ws + off);                  off += (size_t)T_SEQ * BATCH * HID * 2;

    hipMemsetAsync(ctr, 0, flag_bytes, stream);

    auto conv = [&](const float* in, u16* o, int n) {
        int n4 = n / 4;
        cvt_f32_bf16<<<(n4 + 255) / 256, 256, 0, stream>>>(in, o, n4);
    };
    conv(x,    x_bf,    T_SEQ * BATCH * IN0);
    conv(wih0, wih0_bf, G4 * IN0);
    conv(whh0, whh0_bf, G4 * HID);
    conv(wih1, wih1_bf, G4 * HID);
    conv(whh1, whh1_bf, G4 * HID);
    conv(fcw,  fcw_bf,  OUTF * HID);

    float* outFC = out;
    float* hN = out + (size_t)T_SEQ * BATCH * OUTF;     // [2,B,H]
    float* cN = hN + 2 * BATCH * HID;                   // [2,B,H]

    lstm_fused<<<2 * NWG_L, 256, 0, stream>>>(x_bf, wih0_bf, whh0_bf, b0,
                                              wih1_bf, whh1_bf, b1,
                                              y0, y1, hN, cN, ctr);
    fc_kernel<<<256, 256, 0, stream>>>(y1, fcw_bf, fcb, outFC);
}